// Round 8
// baseline (473.778 us; speedup 1.0000x reference)
//
#include <hip/hip_runtime.h>
#include <hip/hip_bf16.h>
#include <math.h>

typedef float f32x4 __attribute__((ext_vector_type(4)));
typedef short bf16x8 __attribute__((ext_vector_type(8)));

#define H_DIM 4096
#define E_EXP 64
#define NTOK  16384
#define PLANE (E_EXP * H_DIM)      // shorts per w plane = 262144
#define PS    132                  // floats per block partial
#define NBLK  256                  // main blocks: 64 tokens each

// split fp32 -> h + m + l (bf16 each), residual ~2^-27|v|
__device__ __forceinline__ void split8(f32x4 a, f32x4 b, bf16x8 &h, bf16x8 &m, bf16x8 &l){
#pragma unroll
    for (int j = 0; j < 8; j++){
        float v = (j < 4) ? a[j] : b[j - 4];
        __hip_bfloat16 hb = __float2bfloat16(v);
        float r1 = v - __bfloat162float(hb);
        __hip_bfloat16 mb = __float2bfloat16(r1);
        float r2 = r1 - __bfloat162float(mb);
        __hip_bfloat16 lb = __float2bfloat16(r2);
        h[j] = __builtin_bit_cast(short, hb);
        m[j] = __builtin_bit_cast(short, mb);
        l[j] = __builtin_bit_cast(short, lb);
    }
}

#define MFMA __builtin_amdgcn_mfma_f32_16x16x32_bf16

__device__ __forceinline__ void gload_lds(const short* g, char* l){
    __builtin_amdgcn_global_load_lds(
        (const __attribute__((address_space(1))) void*)g,
        (__attribute__((address_space(3))) void*)l, 16, 0, 0);
}

// ---------------------------------------------------------------------------
// Kernel A: pre-split gate_w into 3 bf16 planes [3][E][H] (1.5 MB, L2-resident)
// ---------------------------------------------------------------------------
__global__ __launch_bounds__(256) void moe_wsplit(
    const float* __restrict__ gw, short* __restrict__ wpl)
{
    const int idx = (blockIdx.x * 256 + threadIdx.x) * 8;
    f32x4 a = *(const f32x4*)(gw + idx);
    f32x4 b = *(const f32x4*)(gw + idx + 4);
    bf16x8 h, m, l; split8(a, b, h, m, l);
    *(bf16x8*)(wpl + idx)             = h;
    *(bf16x8*)(wpl + PLANE + idx)     = m;
    *(bf16x8*)(wpl + 2 * PLANE + idx) = l;
}

// ---------------------------------------------------------------------------
// Main: 256 blocks x 256 threads (4 waves), 3 blocks/CU. Block owns 64 tokens;
// wave wv owns tokens [16wv,16wv+16) and FULL K (128 chunks of 32).
// Per chunk: one shared 12 KB w stage via global_load_lds DMA (double-buffered,
// counted vmcnt, raw s_barrier); x split in-register.
// LDS w layout per buf: [plane(3)][kgrp(4)][expert(64)][8 bf16 = 16B].
// ---------------------------------------------------------------------------
__global__ __launch_bounds__(256, 3) void moe_gate_main(
    const float* __restrict__ x, const short* __restrict__ wpl,
    const float* __restrict__ bias, float* __restrict__ out,
    float* __restrict__ part)
{
    __shared__ short wlds[12288];        // [buf][p][kg][e][8] = 24 KB
    __shared__ float ls[64 * 68];        // logits/probs [token][expert] ~17 KB
    __shared__ float bs[64], rs[64], zW[4];
    __shared__ int   ia[64], ib[64];

    const int tid = threadIdx.x, bid = blockIdx.x;
    const int wv = tid >> 6, l = tid & 63, l16 = l & 15, lk = l >> 4;
    const int tok0 = bid * 64;

    if (tid < 64) bs[tid] = bias[tid];

    // staging map: seg = wv*3+i in [0,12) -> (plane, kgrp); lane = expert
    const short* wsrc[3]; int wdst[3];
#pragma unroll
    for (int i = 0; i < 3; i++){
        const int sg = wv * 3 + i, p = sg >> 2, kg = sg & 3;
        wsrc[i] = wpl + p * PLANE + l * H_DIM + kg * 8;
        wdst[i] = p * 4096 + kg * 1024;          // bytes; +buf*12288
    }
    // frag-read base (bytes): lane reads expert g*16+l16, k-slot lk
    const int fb = lk * 1024 + l16 * 16;
    // x source: token tok0+wv*16+l16, cols cc*32 + lk*8
    const float* xbase = x + (size_t)(tok0 + wv * 16 + l16) * H_DIM + lk * 8;

    f32x4 acc[4] = {};

#define STAGE(ccn, BUFW) do {                                               \
    __builtin_amdgcn_sched_barrier(0);                                      \
    _Pragma("unroll")                                                       \
    for (int i_ = 0; i_ < 3; i_++)                                          \
        gload_lds(wsrc[i_] + (ccn) * 32,                                    \
                  (char*)wlds + wdst[i_] + (BUFW) * 12288);                 \
    __builtin_amdgcn_sched_barrier(0);                                      \
} while(0)

#define KPHASE(cc, BUFR, XA, XB, XNA, XNB, DO_NEXT) do {                    \
    if (DO_NEXT) {                                                          \
        STAGE((cc) + 1, ((cc) + 1) & 1);                                    \
        XNA = *(const f32x4*)(xbase + ((cc) + 1) * 32);                     \
        XNB = *(const f32x4*)(xbase + ((cc) + 1) * 32 + 4);                 \
    }                                                                       \
    bf16x8 xh, xm, xl; split8(XA, XB, xh, xm, xl);                          \
    bf16x8 wf[4][3];                                                        \
    _Pragma("unroll")                                                       \
    for (int g_ = 0; g_ < 4; g_++)                                          \
        _Pragma("unroll")                                                   \
        for (int p_ = 0; p_ < 3; p_++)                                      \
            wf[g_][p_] = *(const bf16x8*)((char*)wlds + fb +                \
                           (BUFR) * 12288 + p_ * 4096 + g_ * 256);          \
    _Pragma("unroll")                                                       \
    for (int g_ = 0; g_ < 4; g_++){                                         \
        acc[g_] = MFMA(xh, wf[g_][0], acc[g_], 0, 0, 0);                    \
        acc[g_] = MFMA(xm, wf[g_][0], acc[g_], 0, 0, 0);                    \
        acc[g_] = MFMA(xh, wf[g_][1], acc[g_], 0, 0, 0);                    \
        acc[g_] = MFMA(xm, wf[g_][1], acc[g_], 0, 0, 0);                    \
        acc[g_] = MFMA(xh, wf[g_][2], acc[g_], 0, 0, 0);                    \
        acc[g_] = MFMA(xl, wf[g_][0], acc[g_], 0, 0, 0);                    \
    }                                                                       \
    if (DO_NEXT) {                                                          \
        asm volatile("s_waitcnt vmcnt(2)" ::: "memory");                    \
        __builtin_amdgcn_sched_barrier(0);                                  \
        __builtin_amdgcn_s_barrier();                                       \
    }                                                                       \
} while(0)

    // prologue: stage chunk 0 -> buf0; load x(0); drain stage; barrier
    STAGE(0, 0);
    f32x4 xeA = *(const f32x4*)(xbase);
    f32x4 xeB = *(const f32x4*)(xbase + 4);
    f32x4 xoA, xoB;
    asm volatile("s_waitcnt vmcnt(2)" ::: "memory");
    __builtin_amdgcn_sched_barrier(0);
    __builtin_amdgcn_s_barrier();

    for (int t = 0; t < 64; t++){
        KPHASE(2 * t,     0, xeA, xeB, xoA, xoB, true);
        KPHASE(2 * t + 1, 1, xoA, xoB, xeA, xeB, (t < 63));
    }

    // ---- C-frags -> logits LDS (rows owned by this wave; no barrier needed) ----
#pragma unroll
    for (int g = 0; g < 4; g++)
#pragma unroll
        for (int r = 0; r < 4; r++)
            ls[(16 * wv + lk * 4 + r) * 68 + g * 16 + l16] = acc[g][r];

    // ---- per-token epilogue: 4 lanes/token (16 experts each), own wave's rows ----
    {
        const int t = tid >> 2, s4 = tid & 3, eb0 = s4 * 16;
        const float invTemp = (1.0f / 3.0f);
        float m1 = -1e30f, m2 = -1e30f; int i1 = 0, i2 = 0;
        for (int j = 0; j < 16; ++j){
            const int e = eb0 + j;
            float v = (ls[t * 68 + e] + bs[e]) * invTemp;
            ls[t * 68 + e] = v;
            if (v > m1)      { m2 = m1; i2 = i1; m1 = v; i1 = e; }
            else if (v > m2) { m2 = v;  i2 = e; }
        }
#pragma unroll
        for (int off = 1; off <= 2; off <<= 1){
            float om1 = __shfl_xor(m1, off), om2 = __shfl_xor(m2, off);
            int   oi1 = __shfl_xor(i1, off), oi2 = __shfl_xor(i2, off);
            bool sw = (om1 > m1) || (om1 == m1 && oi1 < i1);
            float n1 = sw ? om1 : m1;  int ni1 = sw ? oi1 : i1;
            float lm = sw ? m1  : om1; int li  = sw ? i1  : oi1;
            float w2 = sw ? om2 : m2;  int wi  = sw ? oi2 : i2;
            bool s2 = (lm > w2) || (lm == w2 && li < wi);
            m1 = n1; i1 = ni1;
            m2 = s2 ? lm : w2; i2 = s2 ? li : wi;
        }
        float ssum = 0.f;
        for (int j = 0; j < 16; ++j){
            const int e = eb0 + j;
            float p = __expf(ls[t * 68 + e] - m1);
            ls[t * 68 + e] = p;
            ssum += p;
        }
        ssum += __shfl_xor(ssum, 1);
        ssum += __shfl_xor(ssum, 2);

        float zsq = 0.f;
        if (s4 == 0){
            rs[t] = 1.0f / ssum; ia[t] = i1; ib[t] = i2;
            float p2    = __expf(m2 - m1);
            float inv12 = 1.0f / (1.0f + p2);
            out[(size_t)(tok0 + t) * 2 + 0] = inv12;
            out[(size_t)(tok0 + t) * 2 + 1] = p2 * inv12;
            out[(size_t)NTOK * 2 + (size_t)(tok0 + t) * 2 + 0] = (float)i1;
            out[(size_t)NTOK * 2 + (size_t)(tok0 + t) * 2 + 1] = (float)i2;
            float lse = m1 + logf(ssum);
            zsq = lse * lse;
        }
#pragma unroll
        for (int o = 32; o; o >>= 1) zsq += __shfl_xor(zsq, o);
        if ((tid & 63) == 0) zW[tid >> 6] = zsq;
    }
    __syncthreads();

    // ---- per-expert block partials: lane = expert ----
    if (tid < 64){
        float psum = 0.f, csum = 0.f;
        for (int t2 = 0; t2 < 64; ++t2){
            psum += ls[t2 * 68 + tid] * rs[t2];
            csum += (ia[t2] == tid ? 1.f : 0.f) + (ib[t2] == tid ? 1.f : 0.f);
        }
        part[bid * PS + tid]      = psum;
        part[bid * PS + 64 + tid] = csum;
        if (tid == 0) part[bid * PS + 128] = zW[0] + zW[1] + zW[2] + zW[3];
    }
}

// ---------------------------------------------------------------------------
// Loss reduction over NBLK=256 block partials
// ---------------------------------------------------------------------------
__global__ __launch_bounds__(1024) void moe_gate_loss(
    const float* __restrict__ part, float* __restrict__ out)
{
    __shared__ float spS[16][64], scS[16][64], zW[16];
    const int tid = threadIdx.x;
    const int e = tid & 63, g = tid >> 6;
    float sp = 0.f, sc = 0.f;
    for (int b = g; b < NBLK; b += 16){
        sp += part[b * PS + e];
        sc += part[b * PS + 64 + e];
    }
    spS[g][e] = sp; scS[g][e] = sc;
    float z = (tid < NBLK) ? part[tid * PS + 128] : 0.f;
#pragma unroll
    for (int o = 32; o; o >>= 1) z += __shfl_xor(z, o);
    if ((tid & 63) == 0) zW[g] = z;
    __syncthreads();

    if (tid < 64){
        float tsp = 0.f, tsc = 0.f;
#pragma unroll
        for (int q = 0; q < 16; ++q){ tsp += spS[q][tid]; tsc += scS[q][tid]; }
        float zp = (tid < 16) ? zW[tid] : 0.f;
        const float invN = 1.0f / (float)NTOK;
        float dot = (tsc * invN) * (tsp * invN);
#pragma unroll
        for (int o = 32; o; o >>= 1){
            dot += __shfl_xor(dot, o);
            zp  += __shfl_xor(zp, o);
        }
        if (tid == 0)
            out[(size_t)NTOK * 4] = 0.01f * 64.0f * dot + 1e-4f * zp * invN;
    }
}

// ---------------------------------------------------------------------------
extern "C" void kernel_launch(void* const* d_in, const int* in_sizes, int n_in,
                              void* d_out, int out_size, void* d_ws, size_t ws_size,
                              hipStream_t stream)
{
    const float* x    = (const float*)d_in[0];
    const float* gw   = (const float*)d_in[1];
    const float* bias = (const float*)d_in[2];
    float* out = (float*)d_out;

    short* wpl  = (short*)d_ws;                                      // 1.5 MB
    float* part = (float*)((char*)d_ws + 3 * PLANE * sizeof(short)); // 135 KB

    moe_wsplit<<<128, 256, 0, stream>>>(gw, wpl);
    moe_gate_main<<<NBLK, 256, 0, stream>>>(x, wpl, bias, out, part);
    moe_gate_loss<<<1, 1024, 0, stream>>>(part, out);
}

// Round 9
// 425.800 us; speedup vs baseline: 1.1127x; 1.1127x over previous
//
#include <hip/hip_runtime.h>
#include <hip/hip_bf16.h>
#include <math.h>

typedef float f32x4 __attribute__((ext_vector_type(4)));
typedef short bf16x8 __attribute__((ext_vector_type(8)));

#define H_DIM 4096
#define E_EXP 64
#define NTOK  16384
#define PLANE (E_EXP * H_DIM)      // shorts per w plane = 262144
#define PS    132                  // floats per block partial
#define NCMB  256                  // combine blocks (64 tokens each)

// split fp32 -> h + m + l (bf16 each), residual ~2^-27|v|
__device__ __forceinline__ void split8(f32x4 a, f32x4 b, bf16x8 &h, bf16x8 &m, bf16x8 &l){
#pragma unroll
    for (int j = 0; j < 8; j++){
        float v = (j < 4) ? a[j] : b[j - 4];
        __hip_bfloat16 hb = __float2bfloat16(v);
        float r1 = v - __bfloat162float(hb);
        __hip_bfloat16 mb = __float2bfloat16(r1);
        float r2 = r1 - __bfloat162float(mb);
        __hip_bfloat16 lb = __float2bfloat16(r2);
        h[j] = __builtin_bit_cast(short, hb);
        m[j] = __builtin_bit_cast(short, mb);
        l[j] = __builtin_bit_cast(short, lb);
    }
}

#define MFMA __builtin_amdgcn_mfma_f32_16x16x32_bf16

__device__ __forceinline__ void gload_lds(const short* g, char* l){
    __builtin_amdgcn_global_load_lds(
        (const __attribute__((address_space(1))) void*)g,
        (__attribute__((address_space(3))) void*)l, 16, 0, 0);
}

// ---------------------------------------------------------------------------
// Kernel A: pre-split gate_w into 3 bf16 planes [3][E][H] (1.5 MB, L2-resident)
// ---------------------------------------------------------------------------
__global__ __launch_bounds__(256) void moe_wsplit(
    const float* __restrict__ gw, short* __restrict__ wpl)
{
    const int idx = (blockIdx.x * 256 + threadIdx.x) * 8;
    f32x4 a = *(const f32x4*)(gw + idx);
    f32x4 b = *(const f32x4*)(gw + idx + 4);
    bf16x8 h, m, l; split8(a, b, h, m, l);
    *(bf16x8*)(wpl + idx)             = h;
    *(bf16x8*)(wpl + PLANE + idx)     = m;
    *(bf16x8*)(wpl + 2 * PLANE + idx) = l;
}

// ---------------------------------------------------------------------------
// Main: 1024 blocks = 256 token-groups x 4 K-quarters; 4 blocks/CU.
// Block: 4 waves, 64 tokens, K-quarter (32 chunks of 32). Per chunk the block
// stages 12 KB of w via global_load_lds DMA (double-buffered, counted vmcnt,
// raw s_barrier); x split in-register. Writes partial logits to pl.
// LDS w layout per buf: [plane(3)][kgrp(4)][expert(64)][8 bf16 = 16B].
// ---------------------------------------------------------------------------
__global__ __launch_bounds__(256, 4) void moe_gate_main(
    const float* __restrict__ x, const short* __restrict__ wpl,
    float* __restrict__ pl)
{
    __shared__ short wlds[12288];        // [buf][p][kg][e][8] = 24 KB

    const int tid = threadIdx.x, bid = blockIdx.x;
    const int tgb = bid >> 2, kq = bid & 3;
    const int wv = tid >> 6, l = tid & 63, l16 = l & 15, lk = l >> 4;
    const int tok0 = tgb * 64;
    const int k0 = kq * 1024;

    // staging map: seg = wv*3+i in [0,12) -> (plane, kgrp); lane = expert
    const short* wsrc[3]; int wdst[3];
#pragma unroll
    for (int i = 0; i < 3; i++){
        const int sg = wv * 3 + i, p = sg >> 2, kg = sg & 3;
        wsrc[i] = wpl + p * PLANE + l * H_DIM + k0 + kg * 8;
        wdst[i] = p * 4096 + kg * 1024;          // bytes; +buf*12288
    }
    // frag-read base (bytes): lane reads expert g*16+l16, k-slot lk
    const int fb = lk * 1024 + l16 * 16;
    // x source: token tok0+wv*16+l16, cols k0 + cc*32 + lk*8
    const float* xbase = x + (size_t)(tok0 + wv * 16 + l16) * H_DIM + k0 + lk * 8;

    f32x4 acc[4] = {};

#define STAGE(ccn, BUFW) do {                                               \
    __builtin_amdgcn_sched_barrier(0);                                      \
    _Pragma("unroll")                                                       \
    for (int i_ = 0; i_ < 3; i_++)                                          \
        gload_lds(wsrc[i_] + (ccn) * 32,                                    \
                  (char*)wlds + wdst[i_] + (BUFW) * 12288);                 \
    __builtin_amdgcn_sched_barrier(0);                                      \
} while(0)

#define KPHASE(cc, BUFR, XA, XB, XNA, XNB, DO_NEXT) do {                    \
    if (DO_NEXT) {                                                          \
        STAGE((cc) + 1, ((cc) + 1) & 1);                                    \
        XNA = *(const f32x4*)(xbase + ((cc) + 1) * 32);                     \
        XNB = *(const f32x4*)(xbase + ((cc) + 1) * 32 + 4);                 \
    }                                                                       \
    bf16x8 xh, xm, xl; split8(XA, XB, xh, xm, xl);                          \
    bf16x8 wf[4][3];                                                        \
    _Pragma("unroll")                                                       \
    for (int g_ = 0; g_ < 4; g_++)                                          \
        _Pragma("unroll")                                                   \
        for (int p_ = 0; p_ < 3; p_++)                                      \
            wf[g_][p_] = *(const bf16x8*)((char*)wlds + fb +                \
                           (BUFR) * 12288 + p_ * 4096 + g_ * 256);          \
    _Pragma("unroll")                                                       \
    for (int g_ = 0; g_ < 4; g_++){                                         \
        acc[g_] = MFMA(xh, wf[g_][0], acc[g_], 0, 0, 0);                    \
        acc[g_] = MFMA(xm, wf[g_][0], acc[g_], 0, 0, 0);                    \
        acc[g_] = MFMA(xh, wf[g_][1], acc[g_], 0, 0, 0);                    \
        acc[g_] = MFMA(xm, wf[g_][1], acc[g_], 0, 0, 0);                    \
        acc[g_] = MFMA(xh, wf[g_][2], acc[g_], 0, 0, 0);                    \
        acc[g_] = MFMA(xl, wf[g_][0], acc[g_], 0, 0, 0);                    \
    }                                                                       \
    if (DO_NEXT) {                                                          \
        asm volatile("s_waitcnt vmcnt(2)" ::: "memory");                    \
        __builtin_amdgcn_sched_barrier(0);                                  \
        __builtin_amdgcn_s_barrier();                                       \
    }                                                                       \
} while(0)

    // prologue: stage chunk 0 -> buf0; load x(0); drain stage; barrier
    STAGE(0, 0);
    f32x4 xeA = *(const f32x4*)(xbase);
    f32x4 xeB = *(const f32x4*)(xbase + 4);
    f32x4 xoA, xoB;
    asm volatile("s_waitcnt vmcnt(2)" ::: "memory");
    __builtin_amdgcn_sched_barrier(0);
    __builtin_amdgcn_s_barrier();

    for (int t = 0; t < 16; t++){
        KPHASE(2 * t,     0, xeA, xeB, xoA, xoB, true);
        KPHASE(2 * t + 1, 1, xoA, xoB, xeA, xeB, (t < 15));
    }

    // ---- write partial logits: pl[bid][row(64)][expert(64)] ----
    float* plb = pl + (size_t)bid * 4096;
#pragma unroll
    for (int g = 0; g < 4; g++)
#pragma unroll
        for (int r = 0; r < 4; r++)
            plb[(16 * wv + lk * 4 + r) * 64 + g * 16 + l16] = acc[g][r];
}

// ---------------------------------------------------------------------------
// Combine: 256 blocks x 256 threads. Block owns 64 tokens; thread = (token,
// expert-block-of-16). Sums the 4 K-quarter partials, adds bias, temperature,
// softmax + exact top-2 (lowest-index tie-break) + per-block loss partials.
// ---------------------------------------------------------------------------
__global__ __launch_bounds__(256) void moe_combine(
    const float* __restrict__ pl, const float* __restrict__ bias,
    float* __restrict__ out, float* __restrict__ part)
{
    __shared__ float ls[64 * 68];
    __shared__ float rs[64], zW[4];
    __shared__ int   ia[64], ib[64];

    const int tid = threadIdx.x, bid = blockIdx.x;
    const int tok0 = bid * 64;
    const int t = tid >> 2, s4 = tid & 3, eb0 = s4 * 16;

    f32x4 bv[4];
#pragma unroll
    for (int j = 0; j < 4; j++) bv[j] = *(const f32x4*)(bias + eb0 + 4 * j);

    f32x4 v[4] = {};
#pragma unroll
    for (int q = 0; q < 4; q++){
        const float* p = pl + ((size_t)(bid * 4 + q)) * 4096 + t * 64 + eb0;
#pragma unroll
        for (int j = 0; j < 4; j++) v[j] += *(const f32x4*)(p + 4 * j);
    }

    const float invTemp = (1.0f / 3.0f);
    float vals[16];
#pragma unroll
    for (int j = 0; j < 16; j++)
        vals[j] = (v[j >> 2][j & 3] + bv[j >> 2][j & 3]) * invTemp;

    float m1 = -1e30f, m2 = -1e30f; int i1 = 0, i2 = 0;
#pragma unroll
    for (int j = 0; j < 16; j++){
        float vv = vals[j]; const int e = eb0 + j;
        if (vv > m1)      { m2 = m1; i2 = i1; m1 = vv; i1 = e; }
        else if (vv > m2) { m2 = vv; i2 = e; }
    }
    // merge top-2 across the 4-lane quad (lowest index wins ties)
#pragma unroll
    for (int off = 1; off <= 2; off <<= 1){
        float om1 = __shfl_xor(m1, off), om2 = __shfl_xor(m2, off);
        int   oi1 = __shfl_xor(i1, off), oi2 = __shfl_xor(i2, off);
        bool sw = (om1 > m1) || (om1 == m1 && oi1 < i1);
        float n1 = sw ? om1 : m1;  int ni1 = sw ? oi1 : i1;
        float lm = sw ? m1  : om1; int li  = sw ? i1  : oi1;
        float w2 = sw ? om2 : m2;  int wi  = sw ? oi2 : i2;
        bool s2 = (lm > w2) || (lm == w2 && li < wi);
        m1 = n1; i1 = ni1;
        m2 = s2 ? lm : w2; i2 = s2 ? li : wi;
    }
    float ssum = 0.f;
#pragma unroll
    for (int j = 0; j < 16; j++){
        float p = __expf(vals[j] - m1);
        ls[t * 68 + eb0 + j] = p;
        ssum += p;
    }
    ssum += __shfl_xor(ssum, 1);
    ssum += __shfl_xor(ssum, 2);

    float zsq = 0.f;
    if (s4 == 0){
        rs[t] = 1.0f / ssum; ia[t] = i1; ib[t] = i2;
        float p2    = __expf(m2 - m1);
        float inv12 = 1.0f / (1.0f + p2);
        out[(size_t)(tok0 + t) * 2 + 0] = inv12;
        out[(size_t)(tok0 + t) * 2 + 1] = p2 * inv12;
        out[(size_t)NTOK * 2 + (size_t)(tok0 + t) * 2 + 0] = (float)i1;
        out[(size_t)NTOK * 2 + (size_t)(tok0 + t) * 2 + 1] = (float)i2;
        float lse = m1 + logf(ssum);
        zsq = lse * lse;
    }
#pragma unroll
    for (int o = 32; o; o >>= 1) zsq += __shfl_xor(zsq, o);
    if ((tid & 63) == 0) zW[tid >> 6] = zsq;
    __syncthreads();

    // ---- per-expert block partials: lane = expert ----
    if (tid < 64){
        float psum = 0.f, csum = 0.f;
        for (int t2 = 0; t2 < 64; ++t2){
            psum += ls[t2 * 68 + tid] * rs[t2];
            csum += (ia[t2] == tid ? 1.f : 0.f) + (ib[t2] == tid ? 1.f : 0.f);
        }
        part[bid * PS + tid]      = psum;
        part[bid * PS + 64 + tid] = csum;
        if (tid == 0) part[bid * PS + 128] = zW[0] + zW[1] + zW[2] + zW[3];
    }
}

// ---------------------------------------------------------------------------
// Loss reduction over NCMB=256 block partials
// ---------------------------------------------------------------------------
__global__ __launch_bounds__(1024) void moe_gate_loss(
    const float* __restrict__ part, float* __restrict__ out)
{
    __shared__ float spS[16][64], scS[16][64], zW[16];
    const int tid = threadIdx.x;
    const int e = tid & 63, g = tid >> 6;
    float sp = 0.f, sc = 0.f;
    for (int b = g; b < NCMB; b += 16){
        sp += part[b * PS + e];
        sc += part[b * PS + 64 + e];
    }
    spS[g][e] = sp; scS[g][e] = sc;
    float z = (tid < NCMB) ? part[tid * PS + 128] : 0.f;
#pragma unroll
    for (int o = 32; o; o >>= 1) z += __shfl_xor(z, o);
    if ((tid & 63) == 0) zW[g] = z;
    __syncthreads();

    if (tid < 64){
        float tsp = 0.f, tsc = 0.f;
#pragma unroll
        for (int q = 0; q < 16; ++q){ tsp += spS[q][tid]; tsc += scS[q][tid]; }
        float zp = (tid < 16) ? zW[tid] : 0.f;
        const float invN = 1.0f / (float)NTOK;
        float dot = (tsc * invN) * (tsp * invN);
#pragma unroll
        for (int o = 32; o; o >>= 1){
            dot += __shfl_xor(dot, o);
            zp  += __shfl_xor(zp, o);
        }
        if (tid == 0)
            out[(size_t)NTOK * 4] = 0.01f * 64.0f * dot + 1e-4f * zp * invN;
    }
}

// ---------------------------------------------------------------------------
extern "C" void kernel_launch(void* const* d_in, const int* in_sizes, int n_in,
                              void* d_out, int out_size, void* d_ws, size_t ws_size,
                              hipStream_t stream)
{
    const float* x    = (const float*)d_in[0];
    const float* gw   = (const float*)d_in[1];
    const float* bias = (const float*)d_in[2];
    float* out = (float*)d_out;

    short* wpl  = (short*)d_ws;                                        // 1.5 MB
    float* pl   = (float*)((char*)d_ws + 3 * PLANE * sizeof(short));   // 16 MB
    float* part = (float*)((char*)d_ws + 3 * PLANE * sizeof(short)
                           + (size_t)1024 * 4096 * sizeof(float));     // 135 KB

    moe_wsplit<<<128, 256, 0, stream>>>(gw, wpl);
    moe_gate_main<<<1024, 256, 0, stream>>>(x, wpl, pl);
    moe_combine<<<NCMB, 256, 0, stream>>>(pl, bias, out, part);
    moe_gate_loss<<<1, 1024, 0, stream>>>(part, out);
}

// Round 10
// 417.396 us; speedup vs baseline: 1.1351x; 1.0201x over previous
//
#include <hip/hip_runtime.h>
#include <hip/hip_bf16.h>
#include <math.h>

typedef float f32x4 __attribute__((ext_vector_type(4)));
typedef short bf16x8 __attribute__((ext_vector_type(8)));

#define H_DIM 4096
#define E_EXP 64
#define NTOK  16384
#define PLANE (E_EXP * H_DIM)      // shorts per w plane = 262144
#define PS    132                  // floats per block partial
#define NCMB  256                  // combine blocks (64 tokens each)

// split fp32 -> h + m + l (bf16 each), residual ~2^-27|v|
__device__ __forceinline__ void split8(f32x4 a, f32x4 b, bf16x8 &h, bf16x8 &m, bf16x8 &l){
#pragma unroll
    for (int j = 0; j < 8; j++){
        float v = (j < 4) ? a[j] : b[j - 4];
        __hip_bfloat16 hb = __float2bfloat16(v);
        float r1 = v - __bfloat162float(hb);
        __hip_bfloat16 mb = __float2bfloat16(r1);
        float r2 = r1 - __bfloat162float(mb);
        __hip_bfloat16 lb = __float2bfloat16(r2);
        h[j] = __builtin_bit_cast(short, hb);
        m[j] = __builtin_bit_cast(short, mb);
        l[j] = __builtin_bit_cast(short, lb);
    }
}

#define MFMA __builtin_amdgcn_mfma_f32_16x16x32_bf16

__device__ __forceinline__ void gload_lds(const short* g, char* l){
    __builtin_amdgcn_global_load_lds(
        (const __attribute__((address_space(1))) void*)g,
        (__attribute__((address_space(3))) void*)l, 16, 0, 0);
}

// ---------------------------------------------------------------------------
// Kernel A: pre-split gate_w into 3 bf16 planes [3][E][H] (1.5 MB, L2-resident)
// ---------------------------------------------------------------------------
__global__ __launch_bounds__(256) void moe_wsplit(
    const float* __restrict__ gw, short* __restrict__ wpl)
{
    const int idx = (blockIdx.x * 256 + threadIdx.x) * 8;
    f32x4 a = *(const f32x4*)(gw + idx);
    f32x4 b = *(const f32x4*)(gw + idx + 4);
    bf16x8 h, m, l; split8(a, b, h, m, l);
    *(bf16x8*)(wpl + idx)             = h;
    *(bf16x8*)(wpl + PLANE + idx)     = m;
    *(bf16x8*)(wpl + 2 * PLANE + idx) = l;
}

// ---------------------------------------------------------------------------
// Main: 1024 blocks = 256 token-groups x 4 K-quarters; 4 blocks/CU.
// Block: 4 waves, 64 tokens, K-quarter (32 chunks of 32). Per chunk the block
// stages 12 KB of w via global_load_lds DMA (double-buffered, counted vmcnt,
// raw s_barrier). x prefetched DEPTH-2 via 4 rotating register slots, so each
// x pair is issued ~2 phase-times before its forced completion (HBM latency
// covered). Writes partial logits to pl.
// ---------------------------------------------------------------------------
__global__ __launch_bounds__(256, 4) void moe_gate_main(
    const float* __restrict__ x, const short* __restrict__ wpl,
    float* __restrict__ pl)
{
    __shared__ short wlds[12288];        // [buf][p][kg][e][8] = 24 KB

    const int tid = threadIdx.x, bid = blockIdx.x;
    const int tgb = bid >> 2, kq = bid & 3;
    const int wv = tid >> 6, l = tid & 63, l16 = l & 15, lk = l >> 4;
    const int tok0 = tgb * 64;
    const int k0 = kq * 1024;

    // staging map: seg = wv*3+i in [0,12) -> (plane, kgrp); lane = expert
    const short* wsrc[3]; int wdst[3];
#pragma unroll
    for (int i = 0; i < 3; i++){
        const int sg = wv * 3 + i, p = sg >> 2, kg = sg & 3;
        wsrc[i] = wpl + p * PLANE + l * H_DIM + k0 + kg * 8;
        wdst[i] = p * 4096 + kg * 1024;          // bytes; +buf*12288
    }
    // frag-read base (bytes): lane reads expert g*16+l16, k-slot lk
    const int fb = lk * 1024 + l16 * 16;
    // x source: token tok0+wv*16+l16, cols k0 + cc*32 + lk*8
    const float* xbase = x + (size_t)(tok0 + wv * 16 + l16) * H_DIM + k0 + lk * 8;

    f32x4 acc[4] = {};
    f32x4 s0a, s0b, s1a, s1b, s2a, s2b, s3a, s3b;   // 4 x-slots, static names

#define STAGE(ccn, BUFW) do {                                               \
    __builtin_amdgcn_sched_barrier(0);                                      \
    _Pragma("unroll")                                                       \
    for (int i_ = 0; i_ < 3; i_++)                                          \
        gload_lds(wsrc[i_] + (ccn) * 32,                                    \
                  (char*)wlds + wdst[i_] + (BUFW) * 12288);                 \
    __builtin_amdgcn_sched_barrier(0);                                      \
} while(0)

// Phase cc: [optional stage(cc+1)] [optional x(cc+2)->PF slot] split(CUR slot)
// 12 LDS frag reads from buf cc&1, 24 MFMA, [optional counted-vmcnt + barrier]
#define PH(cc, CA, CB, PA, PB, DO_STAGE, DO_X, VMSTR, DO_BAR) do {          \
    if (DO_STAGE) STAGE((cc) + 1, ((cc) + 1) & 1);                          \
    if (DO_X) {                                                             \
        PA = *(const f32x4*)(xbase + ((cc) + 2) * 32);                      \
        PB = *(const f32x4*)(xbase + ((cc) + 2) * 32 + 4);                  \
    }                                                                       \
    bf16x8 xh, xm, xl; split8(CA, CB, xh, xm, xl);                          \
    bf16x8 wf[4][3];                                                        \
    _Pragma("unroll")                                                       \
    for (int g_ = 0; g_ < 4; g_++)                                          \
        _Pragma("unroll")                                                   \
        for (int p_ = 0; p_ < 3; p_++)                                      \
            wf[g_][p_] = *(const bf16x8*)((char*)wlds + fb +                \
                           (((cc) & 1)) * 12288 + p_ * 4096 + g_ * 256);    \
    _Pragma("unroll")                                                       \
    for (int g_ = 0; g_ < 4; g_++){                                         \
        acc[g_] = MFMA(xh, wf[g_][0], acc[g_], 0, 0, 0);                    \
        acc[g_] = MFMA(xm, wf[g_][0], acc[g_], 0, 0, 0);                    \
        acc[g_] = MFMA(xh, wf[g_][1], acc[g_], 0, 0, 0);                    \
        acc[g_] = MFMA(xm, wf[g_][1], acc[g_], 0, 0, 0);                    \
        acc[g_] = MFMA(xh, wf[g_][2], acc[g_], 0, 0, 0);                    \
        acc[g_] = MFMA(xl, wf[g_][0], acc[g_], 0, 0, 0);                    \
    }                                                                       \
    if (DO_BAR) {                                                           \
        asm volatile("s_waitcnt " VMSTR ::: "memory");                      \
        __builtin_amdgcn_sched_barrier(0);                                  \
        __builtin_amdgcn_s_barrier();                                       \
    }                                                                       \
} while(0)

    // prologue: stage chunk0 -> buf0; x(0)->s0, x(1)->s1; drain stage; barrier
    STAGE(0, 0);
    s0a = *(const f32x4*)(xbase);       s0b = *(const f32x4*)(xbase + 4);
    s1a = *(const f32x4*)(xbase + 32);  s1b = *(const f32x4*)(xbase + 36);
    asm volatile("s_waitcnt vmcnt(4)" ::: "memory");
    __builtin_amdgcn_sched_barrier(0);
    __builtin_amdgcn_s_barrier();

    for (int q = 0; q < 7; q++){
        const int c4 = q * 4;
        PH(c4 + 0, s0a, s0b, s2a, s2b, true, true, "vmcnt(2)", true);
        PH(c4 + 1, s1a, s1b, s3a, s3b, true, true, "vmcnt(2)", true);
        PH(c4 + 2, s2a, s2b, s0a, s0b, true, true, "vmcnt(2)", true);
        PH(c4 + 3, s3a, s3b, s1a, s1b, true, true, "vmcnt(2)", true);
    }
    PH(28, s0a, s0b, s2a, s2b, true,  true,  "vmcnt(2)", true);
    PH(29, s1a, s1b, s3a, s3b, true,  true,  "vmcnt(2)", true);
    PH(30, s2a, s2b, s0a, s0b, true,  false, "vmcnt(0)", true);
    PH(31, s3a, s3b, s0a, s0b, false, false, "vmcnt(0)", false);

    // ---- write partial logits: pl[bid][row(64)][expert(64)] ----
    float* plb = pl + (size_t)bid * 4096;
#pragma unroll
    for (int g = 0; g < 4; g++)
#pragma unroll
        for (int r = 0; r < 4; r++)
            plb[(16 * wv + lk * 4 + r) * 64 + g * 16 + l16] = acc[g][r];
}

// ---------------------------------------------------------------------------
// Combine: 256 blocks x 256 threads. Block owns 64 tokens; thread = (token,
// expert-block-of-16). Sums the 4 K-quarter partials, adds bias, temperature,
// softmax + exact top-2 (lowest-index tie-break) + per-block loss partials.
// ---------------------------------------------------------------------------
__global__ __launch_bounds__(256) void moe_combine(
    const float* __restrict__ pl, const float* __restrict__ bias,
    float* __restrict__ out, float* __restrict__ part)
{
    __shared__ float ls[64 * 68];
    __shared__ float rs[64], zW[4];
    __shared__ int   ia[64], ib[64];

    const int tid = threadIdx.x, bid = blockIdx.x;
    const int tok0 = bid * 64;
    const int t = tid >> 2, s4 = tid & 3, eb0 = s4 * 16;

    f32x4 bv[4];
#pragma unroll
    for (int j = 0; j < 4; j++) bv[j] = *(const f32x4*)(bias + eb0 + 4 * j);

    f32x4 v[4] = {};
#pragma unroll
    for (int q = 0; q < 4; q++){
        const float* p = pl + ((size_t)(bid * 4 + q)) * 4096 + t * 64 + eb0;
#pragma unroll
        for (int j = 0; j < 4; j++) v[j] += *(const f32x4*)(p + 4 * j);
    }

    const float invTemp = (1.0f / 3.0f);
    float vals[16];
#pragma unroll
    for (int j = 0; j < 16; j++)
        vals[j] = (v[j >> 2][j & 3] + bv[j >> 2][j & 3]) * invTemp;

    float m1 = -1e30f, m2 = -1e30f; int i1 = 0, i2 = 0;
#pragma unroll
    for (int j = 0; j < 16; j++){
        float vv = vals[j]; const int e = eb0 + j;
        if (vv > m1)      { m2 = m1; i2 = i1; m1 = vv; i1 = e; }
        else if (vv > m2) { m2 = vv; i2 = e; }
    }
    // merge top-2 across the 4-lane quad (lowest index wins ties)
#pragma unroll
    for (int off = 1; off <= 2; off <<= 1){
        float om1 = __shfl_xor(m1, off), om2 = __shfl_xor(m2, off);
        int   oi1 = __shfl_xor(i1, off), oi2 = __shfl_xor(i2, off);
        bool sw = (om1 > m1) || (om1 == m1 && oi1 < i1);
        float n1 = sw ? om1 : m1;  int ni1 = sw ? oi1 : i1;
        float lm = sw ? m1  : om1; int li  = sw ? i1  : oi1;
        float w2 = sw ? om2 : m2;  int wi  = sw ? oi2 : i2;
        bool s2 = (lm > w2) || (lm == w2 && li < wi);
        m1 = n1; i1 = ni1;
        m2 = s2 ? lm : w2; i2 = s2 ? li : wi;
    }
    float ssum = 0.f;
#pragma unroll
    for (int j = 0; j < 16; j++){
        float p = __expf(vals[j] - m1);
        ls[t * 68 + eb0 + j] = p;
        ssum += p;
    }
    ssum += __shfl_xor(ssum, 1);
    ssum += __shfl_xor(ssum, 2);

    float zsq = 0.f;
    if (s4 == 0){
        rs[t] = 1.0f / ssum; ia[t] = i1; ib[t] = i2;
        float p2    = __expf(m2 - m1);
        float inv12 = 1.0f / (1.0f + p2);
        out[(size_t)(tok0 + t) * 2 + 0] = inv12;
        out[(size_t)(tok0 + t) * 2 + 1] = p2 * inv12;
        out[(size_t)NTOK * 2 + (size_t)(tok0 + t) * 2 + 0] = (float)i1;
        out[(size_t)NTOK * 2 + (size_t)(tok0 + t) * 2 + 1] = (float)i2;
        float lse = m1 + logf(ssum);
        zsq = lse * lse;
    }
#pragma unroll
    for (int o = 32; o; o >>= 1) zsq += __shfl_xor(zsq, o);
    if ((tid & 63) == 0) zW[tid >> 6] = zsq;
    __syncthreads();

    // ---- per-expert block partials: lane = expert ----
    if (tid < 64){
        float psum = 0.f, csum = 0.f;
        for (int t2 = 0; t2 < 64; ++t2){
            psum += ls[t2 * 68 + tid] * rs[t2];
            csum += (ia[t2] == tid ? 1.f : 0.f) + (ib[t2] == tid ? 1.f : 0.f);
        }
        part[bid * PS + tid]      = psum;
        part[bid * PS + 64 + tid] = csum;
        if (tid == 0) part[bid * PS + 128] = zW[0] + zW[1] + zW[2] + zW[3];
    }
}

// ---------------------------------------------------------------------------
// Loss reduction over NCMB=256 block partials
// ---------------------------------------------------------------------------
__global__ __launch_bounds__(1024) void moe_gate_loss(
    const float* __restrict__ part, float* __restrict__ out)
{
    __shared__ float spS[16][64], scS[16][64], zW[16];
    const int tid = threadIdx.x;
    const int e = tid & 63, g = tid >> 6;
    float sp = 0.f, sc = 0.f;
    for (int b = g; b < NCMB; b += 16){
        sp += part[b * PS + e];
        sc += part[b * PS + 64 + e];
    }
    spS[g][e] = sp; scS[g][e] = sc;
    float z = (tid < NCMB) ? part[tid * PS + 128] : 0.f;
#pragma unroll
    for (int o = 32; o; o >>= 1) z += __shfl_xor(z, o);
    if ((tid & 63) == 0) zW[g] = z;
    __syncthreads();

    if (tid < 64){
        float tsp = 0.f, tsc = 0.f;
#pragma unroll
        for (int q = 0; q < 16; ++q){ tsp += spS[q][tid]; tsc += scS[q][tid]; }
        float zp = (tid < 16) ? zW[tid] : 0.f;
        const float invN = 1.0f / (float)NTOK;
        float dot = (tsc * invN) * (tsp * invN);
#pragma unroll
        for (int o = 32; o; o >>= 1){
            dot += __shfl_xor(dot, o);
            zp  += __shfl_xor(zp, o);
        }
        if (tid == 0)
            out[(size_t)NTOK * 4] = 0.01f * 64.0f * dot + 1e-4f * zp * invN;
    }
}

// ---------------------------------------------------------------------------
extern "C" void kernel_launch(void* const* d_in, const int* in_sizes, int n_in,
                              void* d_out, int out_size, void* d_ws, size_t ws_size,
                              hipStream_t stream)
{
    const float* x    = (const float*)d_in[0];
    const float* gw   = (const float*)d_in[1];
    const float* bias = (const float*)d_in[2];
    float* out = (float*)d_out;

    short* wpl  = (short*)d_ws;                                        // 1.5 MB
    float* pl   = (float*)((char*)d_ws + 3 * PLANE * sizeof(short));   // 16 MB
    float* part = (float*)((char*)d_ws + 3 * PLANE * sizeof(short)
                           + (size_t)1024 * 4096 * sizeof(float));     // 135 KB

    moe_wsplit<<<128, 256, 0, stream>>>(gw, wpl);
    moe_gate_main<<<1024, 256, 0, stream>>>(x, wpl, pl);
    moe_combine<<<NCMB, 256, 0, stream>>>(pl, bias, out, part);
    moe_gate_loss<<<1, 1024, 0, stream>>>(part, out);
}